// Round 1
// 323.715 us; speedup vs baseline: 1.3829x; 1.3829x over previous
//
#include <hip/hip_runtime.h>
#include <stdint.h>

typedef unsigned short u16;
typedef __attribute__((ext_vector_type(8))) __bf16 bf16x8;
typedef __attribute__((ext_vector_type(4))) float f32x4;

#define AS1 __attribute__((address_space(1)))
#define AS3 __attribute__((address_space(3)))

__device__ __forceinline__ u16 f2b(float f) {
    union { float f; unsigned u; } v; v.f = f;
    return (u16)((v.u + 0x7fffu + ((v.u >> 16) & 1u)) >> 16);
}

// ---------------------------------------------------------------------------
// fp32 -> bf16 convert, 8 elements/thread.
// ---------------------------------------------------------------------------
__global__ __launch_bounds__(256) void cvt_kernel(
    const float* __restrict__ src, u16* __restrict__ dst, int n8)
{
    int i = blockIdx.x * 256 + threadIdx.x;
    if (i >= n8) return;
    const float4* s = (const float4*)src;
    float4 f0 = s[(size_t)i * 2], f1 = s[(size_t)i * 2 + 1];
    ushort4 a, b;
    a.x = f2b(f0.x); a.y = f2b(f0.y); a.z = f2b(f0.z); a.w = f2b(f0.w);
    b.x = f2b(f1.x); b.y = f2b(f1.y); b.z = f2b(f1.z); b.w = f2b(f1.w);
    ((ushort4*)dst)[(size_t)i * 2]     = a;
    ((ushort4*)dst)[(size_t)i * 2 + 1] = b;
}

// ---------------------------------------------------------------------------
// GEMM: C[M,N] = A[M,K](bf16) x B[N,K]^T(bf16); m97-style 128x128 tile.
// ---------------------------------------------------------------------------
template <bool F32OUT>
__device__ __forceinline__ void gemm_tile_body(
    const u16* __restrict__ A, const u16* __restrict__ B, void* __restrict__ Cp,
    int K, int ldc, int mb, int nb, int cb, u16* As, u16* Bs)
{
    const int t  = threadIdx.x;
    const int l  = t & 63, w = t >> 6;
    const int wm = w >> 1, wn = w & 1;
    const int lr = l & 15, lg = l >> 4;

    f32x4 acc[4][4];
#pragma unroll
    for (int i = 0; i < 4; ++i)
#pragma unroll
        for (int j = 0; j < 4; ++j) acc[i][j] = f32x4{0.f, 0.f, 0.f, 0.f};

    for (int k0 = 0; k0 < K; k0 += 32) {
        __syncthreads();
#pragma unroll
        for (int i = 0; i < 2; ++i) {
            int chunk = i * 256 + t;
            int row   = chunk >> 2;
            int c8    = (chunk & 3) << 3;
            const u16* ga = A + (size_t)(mb + row) * K + k0 + c8;
            const u16* gb = B + (size_t)(nb + row) * K + k0 + c8;
            u16* la = As + (i * 256 + w * 64) * 8;
            u16* lb = Bs + (i * 256 + w * 64) * 8;
            __builtin_amdgcn_global_load_lds((AS1 unsigned int*)ga, (AS3 unsigned int*)la, 16, 0, 0);
            __builtin_amdgcn_global_load_lds((AS1 unsigned int*)gb, (AS3 unsigned int*)lb, 16, 0, 0);
        }
        __syncthreads();
        bf16x8 af[4], bfr[4];
#pragma unroll
        for (int mi = 0; mi < 4; ++mi)
            af[mi] = *(const bf16x8*)(As + (wm * 64 + mi * 16 + lr) * 32 + lg * 8);
#pragma unroll
        for (int ni = 0; ni < 4; ++ni)
            bfr[ni] = *(const bf16x8*)(Bs + (wn * 64 + ni * 16 + lr) * 32 + lg * 8);
#pragma unroll
        for (int mi = 0; mi < 4; ++mi)
#pragma unroll
            for (int ni = 0; ni < 4; ++ni)
                acc[mi][ni] = __builtin_amdgcn_mfma_f32_16x16x32_bf16(af[mi], bfr[ni], acc[mi][ni], 0, 0, 0);
    }
#pragma unroll
    for (int mi = 0; mi < 4; ++mi)
#pragma unroll
        for (int ni = 0; ni < 4; ++ni) {
            int col = cb + wn * 64 + ni * 16 + lr;
#pragma unroll
            for (int v = 0; v < 4; ++v) {
                int row = mb + wm * 64 + mi * 16 + lg * 4 + v;
                if (F32OUT)
                    ((float*)Cp)[(size_t)row * ldc + col] = acc[mi][ni][v];
                else
                    ((u16*)Cp)[(size_t)row * ldc + col] = f2b(acc[mi][ni][v]);
            }
        }
}

__global__ __launch_bounds__(256, 2) void gemm_qkv_kernel(
    const u16* __restrict__ X, const u16* __restrict__ W3,
    u16* __restrict__ QKV)
{
    __shared__ __attribute__((aligned(16))) u16 As[128 * 32];
    __shared__ __attribute__((aligned(16))) u16 Bs[128 * 32];
    int wsel = blockIdx.y >> 3;
    const u16* B = W3 + (size_t)wsel * 1024 * 1024;
    int nb = (blockIdx.y & 7) * 128;
    gemm_tile_body<false>(X, B, QKV, 1024, 3072, blockIdx.x * 128, nb, wsel * 1024 + nb, As, Bs);
}

__global__ __launch_bounds__(256, 2) void gemm_out_kernel(
    const u16* __restrict__ A, const u16* __restrict__ B, float* __restrict__ C)
{
    __shared__ __attribute__((aligned(16))) u16 As[128 * 32];
    __shared__ __attribute__((aligned(16))) u16 Bs[128 * 32];
    int nb = blockIdx.y * 128;
    gemm_tile_body<true>(A, B, C, 1024, 1024, blockIdx.x * 128, nb, nb, As, Bs);
}

// ---------------------------------------------------------------------------
// Causal flash attention. qkv: [8192,3072] bf16 (Q|K|V col-blocks, head=64).
// Pairing: block bx handles q-tiles {bx, 15-bx} -> every block = 34 k-tiles.
// XOR-swizzled Vt / P stores kill the 16-way / 4-way LDS write conflicts.
// K/V tile prefetched into regs one iteration ahead (latency hides under
// QK^T + softmax + PV of the current tile).
// ---------------------------------------------------------------------------
#define SEQ  2048
#define PSTR 72
#define NQT  16

__device__ __forceinline__ void attn_qtile(
    const u16* __restrict__ Qg, const u16* __restrict__ Kg, const u16* __restrict__ Vg,
    u16* __restrict__ outp, int b, int h, int qt,
    u16* QP, u16* Ks, u16* Vt)
{
    const int t  = threadIdx.x;
    const int l  = t & 63, w = t >> 6;
    const int lr = l & 15, lg = l >> 4;
    const int q0 = qt * 128;
    const int sr = t >> 3;          // staging row within 32-row chunk
    const int sc = (t & 7) << 3;    // staging col (8 u16 per thread)
    const int vswz = (t & 7) << 3;  // == ((d>>3)&7)<<3 for d in [sc, sc+8)

    // ---- stage Q tile, extract per-wave fragments ----
    __syncthreads();                // all waves done with QP/Ks/Vt of prev tile
#pragma unroll
    for (int i = 0; i < 4; ++i) {
        int r = sr + i * 32;
        *(uint4*)(QP + r * PSTR + sc) = *(const uint4*)(Qg + (size_t)(q0 + r) * 3072 + sc);
    }
    __syncthreads();
    bf16x8 qf[2][2];
#pragma unroll
    for (int mi = 0; mi < 2; ++mi)
#pragma unroll
        for (int ks = 0; ks < 2; ++ks)
            qf[mi][ks] = *(const bf16x8*)(QP + (w * 32 + mi * 16 + lr) * PSTR + ks * 32 + lg * 8);
    // (no barrier needed: each wave only re-writes its own QP rows as P later)

    // ---- prefetch K/V tile 0 into registers ----
    uint4 kpf[2], vpf[2];
#pragma unroll
    for (int i = 0; i < 2; ++i) {
        int r = sr + i * 32;
        kpf[i] = *(const uint4*)(Kg + (size_t)r * 3072 + sc);
        vpf[i] = *(const uint4*)(Vg + (size_t)r * 3072 + sc);
    }

    f32x4 o[2][4];
#pragma unroll
    for (int mi = 0; mi < 2; ++mi)
#pragma unroll
        for (int nd = 0; nd < 4; ++nd) o[mi][nd] = f32x4{0.f, 0.f, 0.f, 0.f};
    float mrow[2][4], lrow[2][4];
#pragma unroll
    for (int mi = 0; mi < 2; ++mi)
#pragma unroll
        for (int v = 0; v < 4; ++v) { mrow[mi][v] = -__builtin_inff(); lrow[mi][v] = 0.f; }

    const int xw  = (lg >> 1) << 4;          // P-store col XOR (row>>3 & 1)<<4
    const int xrd = ((lr >> 3) & 1) << 4;    // P-read  col XOR

    const int nkt = 2 * qt + 2;
    for (int kt = 0; kt < nkt; ++kt) {
        const int k0 = kt * 64;
        __syncthreads();            // all waves done reading prev K/V tile
        // ---- commit prefetched K/V tile to LDS ----
#pragma unroll
        for (int i = 0; i < 2; ++i) {
            int r = sr + i * 32;
            *(uint4*)(Ks + r * PSTR + sc) = kpf[i];
            int rs = r ^ vswz;      // swizzled column: 16-way -> 2-way conflict
            uint4 vv = vpf[i];
            Vt[(sc + 0) * PSTR + rs] = (u16)(vv.x & 0xffff);
            Vt[(sc + 1) * PSTR + rs] = (u16)(vv.x >> 16);
            Vt[(sc + 2) * PSTR + rs] = (u16)(vv.y & 0xffff);
            Vt[(sc + 3) * PSTR + rs] = (u16)(vv.y >> 16);
            Vt[(sc + 4) * PSTR + rs] = (u16)(vv.z & 0xffff);
            Vt[(sc + 5) * PSTR + rs] = (u16)(vv.z >> 16);
            Vt[(sc + 6) * PSTR + rs] = (u16)(vv.w & 0xffff);
            Vt[(sc + 7) * PSTR + rs] = (u16)(vv.w >> 16);
        }
        // ---- issue next tile's loads (complete during compute below) ----
        if (kt + 1 < nkt) {
            const int k0n = k0 + 64;
#pragma unroll
            for (int i = 0; i < 2; ++i) {
                int r = sr + i * 32;
                kpf[i] = *(const uint4*)(Kg + (size_t)(k0n + r) * 3072 + sc);
                vpf[i] = *(const uint4*)(Vg + (size_t)(k0n + r) * 3072 + sc);
            }
        }
        __syncthreads();

        // ---- QK^T ----
        f32x4 s[2][4];
#pragma unroll
        for (int mi = 0; mi < 2; ++mi)
#pragma unroll
            for (int ni = 0; ni < 4; ++ni) s[mi][ni] = f32x4{0.f, 0.f, 0.f, 0.f};
#pragma unroll
        for (int ks = 0; ks < 2; ++ks) {
            bf16x8 kb[4];
#pragma unroll
            for (int ni = 0; ni < 4; ++ni)
                kb[ni] = *(const bf16x8*)(Ks + (ni * 16 + lr) * PSTR + ks * 32 + lg * 8);
#pragma unroll
            for (int mi = 0; mi < 2; ++mi)
#pragma unroll
                for (int ni = 0; ni < 4; ++ni)
                    s[mi][ni] = __builtin_amdgcn_mfma_f32_16x16x32_bf16(qf[mi][ks], kb[ni], s[mi][ni], 0, 0, 0);
        }

        // ---- scale + causal mask ----
        const bool domask = (k0 + 63) > (q0 + w * 32);
#pragma unroll
        for (int mi = 0; mi < 2; ++mi)
#pragma unroll
            for (int ni = 0; ni < 4; ++ni)
#pragma unroll
                for (int v = 0; v < 4; ++v) {
                    float x = s[mi][ni][v] * 0.125f;
                    if (domask) {
                        int qpos = q0 + w * 32 + mi * 16 + lg * 4 + v;
                        int kpos = k0 + ni * 16 + lr;
                        if (kpos > qpos) x = -__builtin_inff();
                    }
                    s[mi][ni][v] = x;
                }

        // ---- online softmax ----
#pragma unroll
        for (int mi = 0; mi < 2; ++mi)
#pragma unroll
            for (int v = 0; v < 4; ++v) {
                float r = fmaxf(fmaxf(s[mi][0][v], s[mi][1][v]), fmaxf(s[mi][2][v], s[mi][3][v]));
                r = fmaxf(r, __shfl_xor(r, 1));
                r = fmaxf(r, __shfl_xor(r, 2));
                r = fmaxf(r, __shfl_xor(r, 4));
                r = fmaxf(r, __shfl_xor(r, 8));
                float mn = fmaxf(mrow[mi][v], r);
                float al = __expf(mrow[mi][v] - mn);
                mrow[mi][v] = mn;
                float sum = 0.f;
#pragma unroll
                for (int ni = 0; ni < 4; ++ni) {
                    float p = __expf(s[mi][ni][v] - mn);
                    s[mi][ni][v] = p;
                    sum += p;
                }
                sum += __shfl_xor(sum, 1);
                sum += __shfl_xor(sum, 2);
                sum += __shfl_xor(sum, 4);
                sum += __shfl_xor(sum, 8);
                lrow[mi][v] = lrow[mi][v] * al + sum;
#pragma unroll
                for (int nd = 0; nd < 4; ++nd) o[mi][nd][v] *= al;
            }

        // ---- P -> LDS (swizzled: 4-way -> 2-way conflict), own-wave rows ----
#pragma unroll
        for (int mi = 0; mi < 2; ++mi)
#pragma unroll
            for (int ni = 0; ni < 4; ++ni)
#pragma unroll
                for (int v = 0; v < 4; ++v)
                    QP[(w * 32 + mi * 16 + lg * 4 + v) * PSTR + ((ni * 16 + lr) ^ xw)] = f2b(s[mi][ni][v]);

        // ---- PV ----
#pragma unroll
        for (int ks = 0; ks < 2; ++ks) {
            bf16x8 pa[2], vb[4];
#pragma unroll
            for (int mi = 0; mi < 2; ++mi)
                pa[mi] = *(const bf16x8*)(QP + (w * 32 + mi * 16 + lr) * PSTR + ((ks * 32 + lg * 8) ^ xrd));
#pragma unroll
            for (int nd = 0; nd < 4; ++nd) {
                int d = nd * 16 + lr;
                vb[nd] = *(const bf16x8*)(Vt + d * PSTR + ((ks * 32 + lg * 8) ^ (((d >> 3) & 7) << 3)));
            }
#pragma unroll
            for (int mi = 0; mi < 2; ++mi)
#pragma unroll
                for (int nd = 0; nd < 4; ++nd)
                    o[mi][nd] = __builtin_amdgcn_mfma_f32_16x16x32_bf16(pa[mi], vb[nd], o[mi][nd], 0, 0, 0);
        }
    }

    // ---- epilogue ----
#pragma unroll
    for (int mi = 0; mi < 2; ++mi)
#pragma unroll
        for (int v = 0; v < 4; ++v) {
            float inv = 1.f / lrow[mi][v];
            int row = q0 + w * 32 + mi * 16 + lg * 4 + v;
#pragma unroll
            for (int nd = 0; nd < 4; ++nd) {
                int col = h * 64 + nd * 16 + lr;
                outp[(size_t)(b * SEQ + row) * 1024 + col] = f2b(o[mi][nd][v] * inv);
            }
        }
}

__global__ __launch_bounds__(256, 2) void attn_kernel(
    const u16* __restrict__ qkv, u16* __restrict__ outp)
{
    __shared__ __attribute__((aligned(16))) u16 QP[128 * PSTR];
    __shared__ __attribute__((aligned(16))) u16 Ks[64 * PSTR];
    __shared__ __attribute__((aligned(16))) u16 Vt[64 * PSTR];

    const int bh = blockIdx.y;
    const int b  = bh >> 4, h = bh & 15;
    const u16* Qg = qkv + (size_t)b * SEQ * 3072 + h * 64;
    const u16* Kg = Qg + 1024;
    const u16* Vg = Qg + 2048;

    // Complementary pair: (2*bx+2) + (2*(15-bx)+2) = 34 k-tiles for every block.
    attn_qtile(Qg, Kg, Vg, outp, b, h, (int)blockIdx.x,           QP, Ks, Vt);
    attn_qtile(Qg, Kg, Vg, outp, b, h, NQT - 1 - (int)blockIdx.x, QP, Ks, Vt);
}

// ---------------------------------------------------------------------------
extern "C" void kernel_launch(void* const* d_in, const int* in_sizes, int n_in,
                              void* d_out, int out_size, void* d_ws, size_t ws_size,
                              hipStream_t stream)
{
    (void)in_sizes; (void)n_in; (void)out_size; (void)ws_size;
    const float* x  = (const float*)d_in[0];
    const float* Wq = (const float*)d_in[1];
    const float* Wk = (const float*)d_in[2];
    const float* Wv = (const float*)d_in[3];
    const float* Wo = (const float*)d_in[4];

    u16*   qkv = (u16*)d_ws;                     // [8192,3072] bf16
    u16*   xb  = qkv + (size_t)8192 * 3072;      // [8192,1024] bf16
    u16*   att = xb;                             // alias: xb dead after QKV GEMM
    u16*   w3  = (u16*)d_out;                    // Wq|Wk|Wv bf16 scratch
    u16*   wob = qkv;                            // Wo bf16 -> dead qkv region
    float* out = (float*)d_out;                  // final [8192,1024] fp32

    cvt_kernel<<<dim3(4096), 256, 0, stream>>>(x,  xb,              1048576);
    cvt_kernel<<<dim3(512),  256, 0, stream>>>(Wq, w3,              131072);
    cvt_kernel<<<dim3(512),  256, 0, stream>>>(Wk, w3 + (1u << 20), 131072);
    cvt_kernel<<<dim3(512),  256, 0, stream>>>(Wv, w3 + (2u << 20), 131072);

    gemm_qkv_kernel<<<dim3(64, 24), 256, 0, stream>>>(xb, w3, qkv);
    attn_kernel   <<<dim3(8, 64), 256, 0, stream>>>(qkv, att);

    cvt_kernel<<<dim3(512), 256, 0, stream>>>(Wo, wob, 131072);
    gemm_out_kernel<<<dim3(64, 8), 256, 0, stream>>>(att, wob, out);
}

// Round 2
// 313.649 us; speedup vs baseline: 1.4272x; 1.0321x over previous
//
#include <hip/hip_runtime.h>
#include <stdint.h>

typedef unsigned short u16;
typedef __attribute__((ext_vector_type(8))) __bf16 bf16x8;
typedef __attribute__((ext_vector_type(4))) float f32x4;

#define AS1 __attribute__((address_space(1)))
#define AS3 __attribute__((address_space(3)))
#define LOG2E 1.4426950408889634f

__device__ __forceinline__ u16 f2bf(float f) {
    union { __bf16 h; u16 u; } cv;
    cv.h = (__bf16)f;   // native cvt (RTNE), compiler pairs into v_cvt_pk_bf16_f32
    return cv.u;
}

// ---------------------------------------------------------------------------
// fp32 -> bf16 convert, 8 elements/thread.
// ---------------------------------------------------------------------------
__global__ __launch_bounds__(256) void cvt_kernel(
    const float* __restrict__ src, u16* __restrict__ dst, int n8)
{
    int i = blockIdx.x * 256 + threadIdx.x;
    if (i >= n8) return;
    const float4* s = (const float4*)src;
    float4 f0 = s[(size_t)i * 2], f1 = s[(size_t)i * 2 + 1];
    ushort4 a, b;
    a.x = f2bf(f0.x); a.y = f2bf(f0.y); a.z = f2bf(f0.z); a.w = f2bf(f0.w);
    b.x = f2bf(f1.x); b.y = f2bf(f1.y); b.z = f2bf(f1.z); b.w = f2bf(f1.w);
    ((ushort4*)dst)[(size_t)i * 2]     = a;
    ((ushort4*)dst)[(size_t)i * 2 + 1] = b;
}

// Wq|Wk|Wv in one launch; Wq gets the 1/8 attention scale folded in
// (power-of-2 scale is exact in fp32 and commutes with bf16 rounding).
__global__ __launch_bounds__(256) void cvt3_kernel(
    const float* __restrict__ wq, const float* __restrict__ wk,
    const float* __restrict__ wv, u16* __restrict__ dst)
{
    int i = blockIdx.x * 256 + threadIdx.x;          // 0 .. 3*131072
    int seg = i >> 17;
    const float* s = (seg == 0) ? wq : (seg == 1) ? wk : wv;
    float sc = (seg == 0) ? 0.125f : 1.0f;
    int j = i & 131071;
    const float4* sp = (const float4*)s;
    float4 f0 = sp[(size_t)j * 2], f1 = sp[(size_t)j * 2 + 1];
    ushort4 a, b;
    a.x = f2bf(f0.x * sc); a.y = f2bf(f0.y * sc); a.z = f2bf(f0.z * sc); a.w = f2bf(f0.w * sc);
    b.x = f2bf(f1.x * sc); b.y = f2bf(f1.y * sc); b.z = f2bf(f1.z * sc); b.w = f2bf(f1.w * sc);
    ((ushort4*)dst)[(size_t)i * 2]     = a;
    ((ushort4*)dst)[(size_t)i * 2 + 1] = b;
}

// ---------------------------------------------------------------------------
// GEMM: C[M,N] = A[M,K](bf16) x B[N,K]^T(bf16); m97-style 128x128 tile.
// ---------------------------------------------------------------------------
template <bool F32OUT>
__device__ __forceinline__ void gemm_tile_body(
    const u16* __restrict__ A, const u16* __restrict__ B, void* __restrict__ Cp,
    int K, int ldc, int mb, int nb, int cb, u16* As, u16* Bs)
{
    const int t  = threadIdx.x;
    const int l  = t & 63, w = t >> 6;
    const int wm = w >> 1, wn = w & 1;
    const int lr = l & 15, lg = l >> 4;

    f32x4 acc[4][4];
#pragma unroll
    for (int i = 0; i < 4; ++i)
#pragma unroll
        for (int j = 0; j < 4; ++j) acc[i][j] = f32x4{0.f, 0.f, 0.f, 0.f};

    for (int k0 = 0; k0 < K; k0 += 32) {
        __syncthreads();
#pragma unroll
        for (int i = 0; i < 2; ++i) {
            int chunk = i * 256 + t;
            int row   = chunk >> 2;
            int c8    = (chunk & 3) << 3;
            const u16* ga = A + (size_t)(mb + row) * K + k0 + c8;
            const u16* gb = B + (size_t)(nb + row) * K + k0 + c8;
            u16* la = As + (i * 256 + w * 64) * 8;
            u16* lb = Bs + (i * 256 + w * 64) * 8;
            __builtin_amdgcn_global_load_lds((AS1 unsigned int*)ga, (AS3 unsigned int*)la, 16, 0, 0);
            __builtin_amdgcn_global_load_lds((AS1 unsigned int*)gb, (AS3 unsigned int*)lb, 16, 0, 0);
        }
        __syncthreads();
        bf16x8 af[4], bfr[4];
#pragma unroll
        for (int mi = 0; mi < 4; ++mi)
            af[mi] = *(const bf16x8*)(As + (wm * 64 + mi * 16 + lr) * 32 + lg * 8);
#pragma unroll
        for (int ni = 0; ni < 4; ++ni)
            bfr[ni] = *(const bf16x8*)(Bs + (wn * 64 + ni * 16 + lr) * 32 + lg * 8);
#pragma unroll
        for (int mi = 0; mi < 4; ++mi)
#pragma unroll
            for (int ni = 0; ni < 4; ++ni)
                acc[mi][ni] = __builtin_amdgcn_mfma_f32_16x16x32_bf16(af[mi], bfr[ni], acc[mi][ni], 0, 0, 0);
    }
#pragma unroll
    for (int mi = 0; mi < 4; ++mi)
#pragma unroll
        for (int ni = 0; ni < 4; ++ni) {
            int col = cb + wn * 64 + ni * 16 + lr;
#pragma unroll
            for (int v = 0; v < 4; ++v) {
                int row = mb + wm * 64 + mi * 16 + lg * 4 + v;
                if (F32OUT)
                    ((float*)Cp)[(size_t)row * ldc + col] = acc[mi][ni][v];
                else
                    ((u16*)Cp)[(size_t)row * ldc + col] = f2bf(acc[mi][ni][v]);
            }
        }
}

__global__ __launch_bounds__(256, 2) void gemm_qkv_kernel(
    const u16* __restrict__ X, const u16* __restrict__ W3,
    u16* __restrict__ QKV)
{
    __shared__ __attribute__((aligned(16))) u16 As[128 * 32];
    __shared__ __attribute__((aligned(16))) u16 Bs[128 * 32];
    int wsel = blockIdx.y >> 3;
    const u16* B = W3 + (size_t)wsel * 1024 * 1024;
    int nb = (blockIdx.y & 7) * 128;
    gemm_tile_body<false>(X, B, QKV, 1024, 3072, blockIdx.x * 128, nb, wsel * 1024 + nb, As, Bs);
}

__global__ __launch_bounds__(256, 2) void gemm_out_kernel(
    const u16* __restrict__ A, const u16* __restrict__ B, float* __restrict__ C)
{
    __shared__ __attribute__((aligned(16))) u16 As[128 * 32];
    __shared__ __attribute__((aligned(16))) u16 Bs[128 * 32];
    int nb = blockIdx.y * 128;
    gemm_tile_body<true>(A, B, C, 1024, 1024, blockIdx.x * 128, nb, nb, As, Bs);
}

// ---------------------------------------------------------------------------
// Causal flash attention. qkv: [8192,3072] bf16 (Q|K|V col-blocks, head=64).
// Q pre-scaled by 1/8 (folded into Wq cvt). exp2-domain online softmax with
// bit-exact defer-rescale (skip mn/al/o-rescale when no row max grew).
// Mask only on diagonal tiles (wave-uniform branch). setprio around MFMA.
// ---------------------------------------------------------------------------
#define SEQ  2048
#define PSTR 72
#define NQT  16

__device__ __forceinline__ void attn_qtile(
    const u16* __restrict__ Qg, const u16* __restrict__ Kg, const u16* __restrict__ Vg,
    u16* __restrict__ outp, int b, int h, int qt,
    u16* QP, u16* Ks, u16* Vt)
{
    const int t  = threadIdx.x;
    const int l  = t & 63, w = t >> 6;
    const int lr = l & 15, lg = l >> 4;
    const int q0 = qt * 128;
    const int sr = t >> 3;          // staging row within 32-row chunk
    const int sc = (t & 7) << 3;    // staging col (8 u16 per thread)
    const int vswz = (t & 7) << 3;  // Vt store swizzle

    // ---- stage Q tile, extract per-wave fragments ----
    __syncthreads();                // all waves done with QP/Ks/Vt of prev q-tile
#pragma unroll
    for (int i = 0; i < 4; ++i) {
        int r = sr + i * 32;
        *(uint4*)(QP + r * PSTR + sc) = *(const uint4*)(Qg + (size_t)(q0 + r) * 3072 + sc);
    }
    __syncthreads();
    bf16x8 qf[2][2];
#pragma unroll
    for (int mi = 0; mi < 2; ++mi)
#pragma unroll
        for (int ks = 0; ks < 2; ++ks)
            qf[mi][ks] = *(const bf16x8*)(QP + (w * 32 + mi * 16 + lr) * PSTR + ks * 32 + lg * 8);
    // (no barrier needed: each wave only re-writes its own QP rows as P later)

    // ---- prefetch K/V tile 0 into registers ----
    uint4 kpf[2], vpf[2];
#pragma unroll
    for (int i = 0; i < 2; ++i) {
        int r = sr + i * 32;
        kpf[i] = *(const uint4*)(Kg + (size_t)r * 3072 + sc);
        vpf[i] = *(const uint4*)(Vg + (size_t)r * 3072 + sc);
    }

    f32x4 o[2][4];
#pragma unroll
    for (int mi = 0; mi < 2; ++mi)
#pragma unroll
        for (int nd = 0; nd < 4; ++nd) o[mi][nd] = f32x4{0.f, 0.f, 0.f, 0.f};
    float mrow[2][4], mrowL[2][4], lrow[2][4];
#pragma unroll
    for (int mi = 0; mi < 2; ++mi)
#pragma unroll
        for (int v = 0; v < 4; ++v) {
            mrow[mi][v]  = -__builtin_inff();
            mrowL[mi][v] = -__builtin_inff();
            lrow[mi][v]  = 0.f;
        }

    const int xw  = (lg >> 1) << 4;          // P-store col XOR
    const int xrd = ((lr >> 3) & 1) << 4;    // P-read  col XOR

    const int nkt = 2 * qt + 2;
    for (int kt = 0; kt < nkt; ++kt) {
        const int k0 = kt * 64;
        __syncthreads();            // all waves done reading prev K/V tile
        // ---- commit prefetched K/V tile to LDS ----
#pragma unroll
        for (int i = 0; i < 2; ++i) {
            int r = sr + i * 32;
            *(uint4*)(Ks + r * PSTR + sc) = kpf[i];
            int rs = r ^ vswz;
            union { uint4 q; u16 u[8]; } uv; uv.q = vpf[i];
#pragma unroll
            for (int j = 0; j < 8; ++j)
                Vt[(sc + j) * PSTR + rs] = uv.u[j];
        }
        // ---- issue next tile's loads (complete during compute below) ----
        if (kt + 1 < nkt) {
            const int k0n = k0 + 64;
#pragma unroll
            for (int i = 0; i < 2; ++i) {
                int r = sr + i * 32;
                kpf[i] = *(const uint4*)(Kg + (size_t)(k0n + r) * 3072 + sc);
                vpf[i] = *(const uint4*)(Vg + (size_t)(k0n + r) * 3072 + sc);
            }
        }
        __syncthreads();

        // ---- QK^T (Q pre-scaled by 1/8) ----
        f32x4 s[2][4];
#pragma unroll
        for (int mi = 0; mi < 2; ++mi)
#pragma unroll
            for (int ni = 0; ni < 4; ++ni) s[mi][ni] = f32x4{0.f, 0.f, 0.f, 0.f};
        __builtin_amdgcn_s_setprio(1);
#pragma unroll
        for (int ks = 0; ks < 2; ++ks) {
            bf16x8 kb[4];
#pragma unroll
            for (int ni = 0; ni < 4; ++ni)
                kb[ni] = *(const bf16x8*)(Ks + (ni * 16 + lr) * PSTR + ks * 32 + lg * 8);
#pragma unroll
            for (int mi = 0; mi < 2; ++mi)
#pragma unroll
                for (int ni = 0; ni < 4; ++ni)
                    s[mi][ni] = __builtin_amdgcn_mfma_f32_16x16x32_bf16(qf[mi][ks], kb[ni], s[mi][ni], 0, 0, 0);
        }
        __builtin_amdgcn_s_setprio(0);

        // ---- causal mask: wave-uniform, diagonal tiles only ----
        if ((k0 + 63) > (q0 + w * 32)) {
#pragma unroll
            for (int mi = 0; mi < 2; ++mi) {
                int qbase = q0 + w * 32 + mi * 16 + lg * 4;
#pragma unroll
                for (int ni = 0; ni < 4; ++ni) {
                    int kpos = k0 + ni * 16 + lr;
#pragma unroll
                    for (int v = 0; v < 4; ++v)
                        if (kpos > qbase + v) s[mi][ni][v] = -__builtin_inff();
                }
            }
        }

        // ---- online softmax (exp2 domain, defer-rescale thr=0: bit-exact) ----
        float rmax[2][4];
        bool grew = false;
#pragma unroll
        for (int mi = 0; mi < 2; ++mi)
#pragma unroll
            for (int v = 0; v < 4; ++v) {
                float r = fmaxf(fmaxf(s[mi][0][v], s[mi][1][v]), fmaxf(s[mi][2][v], s[mi][3][v]));
                r = fmaxf(r, __shfl_xor(r, 1));
                r = fmaxf(r, __shfl_xor(r, 2));
                r = fmaxf(r, __shfl_xor(r, 4));
                r = fmaxf(r, __shfl_xor(r, 8));
                rmax[mi][v] = r;
                grew |= (r > mrow[mi][v]);
            }
        if (__ballot(grew)) {
#pragma unroll
            for (int mi = 0; mi < 2; ++mi)
#pragma unroll
                for (int v = 0; v < 4; ++v) {
                    float mn  = fmaxf(mrow[mi][v], rmax[mi][v]);
                    float mnL = mn * LOG2E;
                    float al  = __builtin_amdgcn_exp2f(mrowL[mi][v] - mnL);
                    mrow[mi][v]  = mn;
                    mrowL[mi][v] = mnL;
                    lrow[mi][v] *= al;
#pragma unroll
                    for (int nd = 0; nd < 4; ++nd) o[mi][nd][v] *= al;
                }
        }
#pragma unroll
        for (int mi = 0; mi < 2; ++mi)
#pragma unroll
            for (int v = 0; v < 4; ++v) {
                float sum = 0.f;
#pragma unroll
                for (int ni = 0; ni < 4; ++ni) {
                    float p = __builtin_amdgcn_exp2f(
                        __builtin_fmaf(s[mi][ni][v], LOG2E, -mrowL[mi][v]));
                    s[mi][ni][v] = p;
                    sum += p;
                }
                sum += __shfl_xor(sum, 1);
                sum += __shfl_xor(sum, 2);
                sum += __shfl_xor(sum, 4);
                sum += __shfl_xor(sum, 8);
                lrow[mi][v] += sum;
            }

        // ---- P -> LDS (swizzled), own-wave rows only ----
#pragma unroll
        for (int mi = 0; mi < 2; ++mi)
#pragma unroll
            for (int ni = 0; ni < 4; ++ni)
#pragma unroll
                for (int v = 0; v < 4; ++v)
                    QP[(w * 32 + mi * 16 + lg * 4 + v) * PSTR + ((ni * 16 + lr) ^ xw)] = f2bf(s[mi][ni][v]);

        // ---- PV ----
        __builtin_amdgcn_s_setprio(1);
#pragma unroll
        for (int ks = 0; ks < 2; ++ks) {
            bf16x8 pa[2], vb[4];
#pragma unroll
            for (int mi = 0; mi < 2; ++mi)
                pa[mi] = *(const bf16x8*)(QP + (w * 32 + mi * 16 + lr) * PSTR + ((ks * 32 + lg * 8) ^ xrd));
#pragma unroll
            for (int nd = 0; nd < 4; ++nd) {
                int d = nd * 16 + lr;
                vb[nd] = *(const bf16x8*)(Vt + d * PSTR + ((ks * 32 + lg * 8) ^ (((d >> 3) & 7) << 3)));
            }
#pragma unroll
            for (int mi = 0; mi < 2; ++mi)
#pragma unroll
                for (int nd = 0; nd < 4; ++nd)
                    o[mi][nd] = __builtin_amdgcn_mfma_f32_16x16x32_bf16(pa[mi], vb[nd], o[mi][nd], 0, 0, 0);
        }
        __builtin_amdgcn_s_setprio(0);
    }

    // ---- epilogue ----
#pragma unroll
    for (int mi = 0; mi < 2; ++mi)
#pragma unroll
        for (int v = 0; v < 4; ++v) {
            float inv = 1.f / lrow[mi][v];
            int row = q0 + w * 32 + mi * 16 + lg * 4 + v;
#pragma unroll
            for (int nd = 0; nd < 4; ++nd) {
                int col = h * 64 + nd * 16 + lr;
                outp[(size_t)(b * SEQ + row) * 1024 + col] = f2bf(o[mi][nd][v] * inv);
            }
        }
}

__global__ __launch_bounds__(256, 2) void attn_kernel(
    const u16* __restrict__ qkv, u16* __restrict__ outp)
{
    __shared__ __attribute__((aligned(16))) u16 QP[128 * PSTR];
    __shared__ __attribute__((aligned(16))) u16 Ks[64 * PSTR];
    __shared__ __attribute__((aligned(16))) u16 Vt[64 * PSTR];

    // XCD-aware remap (assumes bid%8 -> XCD round-robin; harmless if not):
    // all 8 q-pair blocks of a given (b,h) land on one XCD -> its K/V
    // (512 KB) stays L2-resident; 8 bh per XCD = 4 MB = one XCD L2.
    const int bid = (int)blockIdx.x + (int)blockIdx.y * 8;   // 0..511
    const int xcd = bid & 7;
    const int j   = bid >> 3;          // 0..63
    const int bh  = xcd * 8 + (j & 7);
    const int qp  = j >> 3;            // 0..7: q-tile pair index
    const int b   = bh >> 4, h = bh & 15;

    const u16* Qg = qkv + (size_t)b * SEQ * 3072 + h * 64;
    const u16* Kg = Qg + 1024;
    const u16* Vg = Qg + 2048;

    // Complementary pair: (2*qp+2) + (2*(15-qp)+2) = 34 k-tiles per block.
    attn_qtile(Qg, Kg, Vg, outp, b, h, qp,           QP, Ks, Vt);
    attn_qtile(Qg, Kg, Vg, outp, b, h, NQT - 1 - qp, QP, Ks, Vt);
}

// ---------------------------------------------------------------------------
extern "C" void kernel_launch(void* const* d_in, const int* in_sizes, int n_in,
                              void* d_out, int out_size, void* d_ws, size_t ws_size,
                              hipStream_t stream)
{
    (void)in_sizes; (void)n_in; (void)out_size; (void)ws_size;
    const float* x  = (const float*)d_in[0];
    const float* Wq = (const float*)d_in[1];
    const float* Wk = (const float*)d_in[2];
    const float* Wv = (const float*)d_in[3];
    const float* Wo = (const float*)d_in[4];

    u16*   qkv = (u16*)d_ws;                     // [8192,3072] bf16
    u16*   xb  = qkv + (size_t)8192 * 3072;      // [8192,1024] bf16
    u16*   att = xb;                             // alias: xb dead after QKV GEMM
    u16*   w3  = (u16*)d_out;                    // Wq|Wk|Wv bf16 scratch
    u16*   wob = qkv;                            // Wo bf16 -> dead qkv region
    float* out = (float*)d_out;                  // final [8192,1024] fp32

    cvt_kernel <<<dim3(4096), 256, 0, stream>>>(x, xb, 1048576);
    cvt3_kernel<<<dim3(1536), 256, 0, stream>>>(Wq, Wk, Wv, w3);  // Wq pre-scaled 1/8

    gemm_qkv_kernel<<<dim3(64, 24), 256, 0, stream>>>(xb, w3, qkv);
    attn_kernel   <<<dim3(8, 64), 256, 0, stream>>>(qkv, att);

    cvt_kernel<<<dim3(512), 256, 0, stream>>>(Wo, wob, 131072);
    gemm_out_kernel<<<dim3(64, 8), 256, 0, stream>>>(att, wob, out);
}

// Round 3
// 275.706 us; speedup vs baseline: 1.6236x; 1.1376x over previous
//
#include <hip/hip_runtime.h>
#include <stdint.h>

typedef unsigned short u16;
typedef __attribute__((ext_vector_type(8))) __bf16 bf16x8;
typedef __attribute__((ext_vector_type(4))) float f32x4;

#define AS1 __attribute__((address_space(1)))
#define AS3 __attribute__((address_space(3)))
#define LOG2E 1.4426950408889634f

__device__ __forceinline__ u16 f2bf(float f) {
    union { __bf16 h; u16 u; } cv;
    cv.h = (__bf16)f;   // native cvt (RTNE)
    return cv.u;
}

__device__ __forceinline__ float vmax4(f32x4 x) {
    return fmaxf(fmaxf(x[0], x[1]), fmaxf(x[2], x[3]));
}
__device__ __forceinline__ float vsum4(f32x4 x) {
    return (x[0] + x[1]) + (x[2] + x[3]);
}

// ---------------------------------------------------------------------------
// fp32 -> bf16 convert, 8 elements/thread.
// ---------------------------------------------------------------------------
__global__ __launch_bounds__(256) void cvt_kernel(
    const float* __restrict__ src, u16* __restrict__ dst, int n8)
{
    int i = blockIdx.x * 256 + threadIdx.x;
    if (i >= n8) return;
    const float4* s = (const float4*)src;
    float4 f0 = s[(size_t)i * 2], f1 = s[(size_t)i * 2 + 1];
    ushort4 a, b;
    a.x = f2bf(f0.x); a.y = f2bf(f0.y); a.z = f2bf(f0.z); a.w = f2bf(f0.w);
    b.x = f2bf(f1.x); b.y = f2bf(f1.y); b.z = f2bf(f1.z); b.w = f2bf(f1.w);
    ((ushort4*)dst)[(size_t)i * 2]     = a;
    ((ushort4*)dst)[(size_t)i * 2 + 1] = b;
}

// Wq|Wk|Wv in one launch; Wq gets the 1/8 attention scale folded in.
__global__ __launch_bounds__(256) void cvt3_kernel(
    const float* __restrict__ wq, const float* __restrict__ wk,
    const float* __restrict__ wv, u16* __restrict__ dst)
{
    int i = blockIdx.x * 256 + threadIdx.x;
    int seg = i >> 17;
    const float* s = (seg == 0) ? wq : (seg == 1) ? wk : wv;
    float sc = (seg == 0) ? 0.125f : 1.0f;
    int j = i & 131071;
    const float4* sp = (const float4*)s;
    float4 f0 = sp[(size_t)j * 2], f1 = sp[(size_t)j * 2 + 1];
    ushort4 a, b;
    a.x = f2bf(f0.x * sc); a.y = f2bf(f0.y * sc); a.z = f2bf(f0.z * sc); a.w = f2bf(f0.w * sc);
    b.x = f2bf(f1.x * sc); b.y = f2bf(f1.y * sc); b.z = f2bf(f1.z * sc); b.w = f2bf(f1.w * sc);
    ((ushort4*)dst)[(size_t)i * 2]     = a;
    ((ushort4*)dst)[(size_t)i * 2 + 1] = b;
}

// ---------------------------------------------------------------------------
// GEMM: C[M,N] = A[M,K](bf16) x B[N,K]^T(bf16); m97-style 128x128 tile.
// ---------------------------------------------------------------------------
template <bool F32OUT>
__device__ __forceinline__ void gemm_tile_body(
    const u16* __restrict__ A, const u16* __restrict__ B, void* __restrict__ Cp,
    int K, int ldc, int mb, int nb, int cb, u16* As, u16* Bs)
{
    const int t  = threadIdx.x;
    const int l  = t & 63, w = t >> 6;
    const int wm = w >> 1, wn = w & 1;
    const int lr = l & 15, lg = l >> 4;

    f32x4 acc[4][4];
#pragma unroll
    for (int i = 0; i < 4; ++i)
#pragma unroll
        for (int j = 0; j < 4; ++j) acc[i][j] = f32x4{0.f, 0.f, 0.f, 0.f};

    for (int k0 = 0; k0 < K; k0 += 32) {
        __syncthreads();
#pragma unroll
        for (int i = 0; i < 2; ++i) {
            int chunk = i * 256 + t;
            int row   = chunk >> 2;
            int c8    = (chunk & 3) << 3;
            const u16* ga = A + (size_t)(mb + row) * K + k0 + c8;
            const u16* gb = B + (size_t)(nb + row) * K + k0 + c8;
            u16* la = As + (i * 256 + w * 64) * 8;
            u16* lb = Bs + (i * 256 + w * 64) * 8;
            __builtin_amdgcn_global_load_lds((AS1 unsigned int*)ga, (AS3 unsigned int*)la, 16, 0, 0);
            __builtin_amdgcn_global_load_lds((AS1 unsigned int*)gb, (AS3 unsigned int*)lb, 16, 0, 0);
        }
        __syncthreads();
        bf16x8 af[4], bfr[4];
#pragma unroll
        for (int mi = 0; mi < 4; ++mi)
            af[mi] = *(const bf16x8*)(As + (wm * 64 + mi * 16 + lr) * 32 + lg * 8);
#pragma unroll
        for (int ni = 0; ni < 4; ++ni)
            bfr[ni] = *(const bf16x8*)(Bs + (wn * 64 + ni * 16 + lr) * 32 + lg * 8);
#pragma unroll
        for (int mi = 0; mi < 4; ++mi)
#pragma unroll
            for (int ni = 0; ni < 4; ++ni)
                acc[mi][ni] = __builtin_amdgcn_mfma_f32_16x16x32_bf16(af[mi], bfr[ni], acc[mi][ni], 0, 0, 0);
    }
#pragma unroll
    for (int mi = 0; mi < 4; ++mi)
#pragma unroll
        for (int ni = 0; ni < 4; ++ni) {
            int col = cb + wn * 64 + ni * 16 + lr;
#pragma unroll
            for (int v = 0; v < 4; ++v) {
                int row = mb + wm * 64 + mi * 16 + lg * 4 + v;
                if (F32OUT)
                    ((float*)Cp)[(size_t)row * ldc + col] = acc[mi][ni][v];
                else
                    ((u16*)Cp)[(size_t)row * ldc + col] = f2bf(acc[mi][ni][v]);
            }
        }
}

__global__ __launch_bounds__(256, 2) void gemm_qkv_kernel(
    const u16* __restrict__ X, const u16* __restrict__ W3,
    u16* __restrict__ QKV)
{
    __shared__ __attribute__((aligned(16))) u16 As[128 * 32];
    __shared__ __attribute__((aligned(16))) u16 Bs[128 * 32];
    // Bijective XCD swizzle (nwg=1536): each XCD owns 8 consecutive M-tiles
    // (2 MB of A, L2-resident), streams all of B.
    int bid = (int)blockIdx.x + (int)gridDim.x * (int)blockIdx.y;
    int wg  = (bid & 7) * 192 + (bid >> 3);
    int mx  = wg / 24;
    int my  = wg % 24;
    int wsel = my >> 3;
    const u16* B = W3 + (size_t)wsel * 1024 * 1024;
    int nb = (my & 7) * 128;
    gemm_tile_body<false>(X, B, QKV, 1024, 3072, mx * 128, nb, wsel * 1024 + nb, As, Bs);
}

__global__ __launch_bounds__(256, 2) void gemm_out_kernel(
    const u16* __restrict__ A, const u16* __restrict__ B, float* __restrict__ C)
{
    __shared__ __attribute__((aligned(16))) u16 As[128 * 32];
    __shared__ __attribute__((aligned(16))) u16 Bs[128 * 32];
    int bid = (int)blockIdx.x + (int)gridDim.x * (int)blockIdx.y;  // nwg=512
    int wg  = (bid & 7) * 64 + (bid >> 3);
    int mx  = wg >> 3;
    int my  = wg & 7;
    gemm_tile_body<true>(A, B, C, 1024, 1024, mx * 128, my * 128, my * 128, As, Bs);
}

// ---------------------------------------------------------------------------
// Causal flash attention, swapped-operand MFMA layout:
//   QK: s = mfma(K, Q)  -> lane holds S[k=ni*16+lg*4+v][q=lr]  (q lane-local!)
//   PV: o = mfma(V', P) -> lane holds O[d=nd*16+lg*4+v][q=lr]
// Softmax is per-lane scalar state + in-lane trees + 2 shfls (lg group).
// P pack: 4 consecutive k per fragment -> ushort4 ds_write_b64 (8/tile).
// ---------------------------------------------------------------------------
#define SEQ  2048
#define PSTR 72
#define NQT  16

__device__ __forceinline__ void attn_qtile(
    const u16* __restrict__ Qg, const u16* __restrict__ Kg, const u16* __restrict__ Vg,
    u16* __restrict__ outp, int b, int h, int qt,
    u16* QP, u16* Ks, u16* Vt)
{
    const int t  = threadIdx.x;
    const int l  = t & 63, w = t >> 6;
    const int lr = l & 15, lg = l >> 4;
    const int q0 = qt * 128;
    const int sr = t >> 3;
    const int sc = (t & 7) << 3;
    const int vswz = sc;            // Vt store swizzle

    // ---- stage Q tile, extract per-wave fragments ----
    __syncthreads();
#pragma unroll
    for (int i = 0; i < 4; ++i) {
        int r = sr + i * 32;
        *(uint4*)(QP + r * PSTR + sc) = *(const uint4*)(Qg + (size_t)(q0 + r) * 3072 + sc);
    }
    __syncthreads();
    bf16x8 qf[2][2];
#pragma unroll
    for (int mi = 0; mi < 2; ++mi)
#pragma unroll
        for (int ks = 0; ks < 2; ++ks)
            qf[mi][ks] = *(const bf16x8*)(QP + (w * 32 + mi * 16 + lr) * PSTR + ks * 32 + lg * 8);

    // ---- prefetch K/V tile 0 ----
    uint4 kpf[2], vpf[2];
#pragma unroll
    for (int i = 0; i < 2; ++i) {
        int r = sr + i * 32;
        kpf[i] = *(const uint4*)(Kg + (size_t)r * 3072 + sc);
        vpf[i] = *(const uint4*)(Vg + (size_t)r * 3072 + sc);
    }

    f32x4 o[4][2];                  // [nd][mi]: O[d][q=lr]
#pragma unroll
    for (int nd = 0; nd < 4; ++nd)
#pragma unroll
        for (int mi = 0; mi < 2; ++mi) o[nd][mi] = f32x4{0.f, 0.f, 0.f, 0.f};
    float mrow[2]  = { -__builtin_inff(), -__builtin_inff() };
    float mrowL[2] = { -__builtin_inff(), -__builtin_inff() };
    float lrow[2]  = { 0.f, 0.f };

    const int nkt = 2 * qt + 2;
    for (int kt = 0; kt < nkt; ++kt) {
        const int k0 = kt * 64;
        __syncthreads();
        // ---- commit prefetched K/V tile ----
#pragma unroll
        for (int i = 0; i < 2; ++i) {
            int r = sr + i * 32;
            *(uint4*)(Ks + r * PSTR + sc) = kpf[i];
            int rs = r ^ vswz;
            union { uint4 q; u16 u[8]; } uv; uv.q = vpf[i];
#pragma unroll
            for (int j = 0; j < 8; ++j)
                Vt[(sc + j) * PSTR + rs] = uv.u[j];
        }
        // ---- issue next tile's loads ----
        if (kt + 1 < nkt) {
            const int k0n = k0 + 64;
#pragma unroll
            for (int i = 0; i < 2; ++i) {
                int r = sr + i * 32;
                kpf[i] = *(const uint4*)(Kg + (size_t)(k0n + r) * 3072 + sc);
                vpf[i] = *(const uint4*)(Vg + (size_t)(k0n + r) * 3072 + sc);
            }
        }
        __syncthreads();

        // ---- QK^T (swapped: A=K, B=Q) ----
        f32x4 s[4][2];              // [ni][mi]: S[k][q=lr]
#pragma unroll
        for (int ni = 0; ni < 4; ++ni)
#pragma unroll
            for (int mi = 0; mi < 2; ++mi) s[ni][mi] = f32x4{0.f, 0.f, 0.f, 0.f};
        __builtin_amdgcn_s_setprio(1);
#pragma unroll
        for (int ks = 0; ks < 2; ++ks) {
            bf16x8 kb[4];
#pragma unroll
            for (int ni = 0; ni < 4; ++ni)
                kb[ni] = *(const bf16x8*)(Ks + (ni * 16 + lr) * PSTR + ks * 32 + lg * 8);
#pragma unroll
            for (int ni = 0; ni < 4; ++ni)
#pragma unroll
                for (int mi = 0; mi < 2; ++mi)
                    s[ni][mi] = __builtin_amdgcn_mfma_f32_16x16x32_bf16(kb[ni], qf[mi][ks], s[ni][mi], 0, 0, 0);
        }
        __builtin_amdgcn_s_setprio(0);

        // ---- causal mask: diagonal waves only; qpos lane-local scalar ----
#pragma unroll
        for (int mi = 0; mi < 2; ++mi) {
            if ((k0 + 63) > (q0 + w * 32 + mi * 16)) {
                int qpos = q0 + w * 32 + mi * 16 + lr;
#pragma unroll
                for (int ni = 0; ni < 4; ++ni) {
                    int kb0 = k0 + ni * 16 + lg * 4;
#pragma unroll
                    for (int v = 0; v < 4; ++v)
                        if (kb0 + v > qpos) s[ni][mi][v] = -__builtin_inff();
                }
            }
        }

        // ---- online softmax: in-lane trees + 2 shfls, scalar state ----
        float rmax[2];
        bool grew = false;
#pragma unroll
        for (int mi = 0; mi < 2; ++mi) {
            float r = fmaxf(fmaxf(vmax4(s[0][mi]), vmax4(s[1][mi])),
                            fmaxf(vmax4(s[2][mi]), vmax4(s[3][mi])));
            r = fmaxf(r, __shfl_xor(r, 16));
            r = fmaxf(r, __shfl_xor(r, 32));
            rmax[mi] = r;
            grew |= (r > mrow[mi]);
        }
        if (__ballot(grew)) {
#pragma unroll
            for (int mi = 0; mi < 2; ++mi) {
                float mn  = fmaxf(mrow[mi], rmax[mi]);
                float mnL = mn * LOG2E;
                float al  = __builtin_amdgcn_exp2f(mrowL[mi] - mnL);
                mrow[mi]  = mn;
                mrowL[mi] = mnL;
                lrow[mi] *= al;
#pragma unroll
                for (int nd = 0; nd < 4; ++nd)
#pragma unroll
                    for (int v = 0; v < 4; ++v) o[nd][mi][v] *= al;
            }
        }
#pragma unroll
        for (int mi = 0; mi < 2; ++mi) {
            float nmL = -mrowL[mi];
#pragma unroll
            for (int ni = 0; ni < 4; ++ni)
#pragma unroll
                for (int v = 0; v < 4; ++v)
                    s[ni][mi][v] = __builtin_amdgcn_exp2f(
                        __builtin_fmaf(s[ni][mi][v], LOG2E, nmL));
            float sum = (vsum4(s[0][mi]) + vsum4(s[1][mi]))
                      + (vsum4(s[2][mi]) + vsum4(s[3][mi]));
            sum += __shfl_xor(sum, 16);
            sum += __shfl_xor(sum, 32);
            lrow[mi] += sum;
            // ---- P -> LDS: 4 consecutive k packed per ds_write_b64 ----
            int prow = (w * 32 + mi * 16 + lr) * PSTR + lg * 4;
#pragma unroll
            for (int ni = 0; ni < 4; ++ni) {
                ushort4 u;
                u.x = f2bf(s[ni][mi][0]); u.y = f2bf(s[ni][mi][1]);
                u.z = f2bf(s[ni][mi][2]); u.w = f2bf(s[ni][mi][3]);
                *(ushort4*)(QP + prow + ni * 16) = u;
            }
        }

        // ---- PV (swapped: A=V', B=P) ----
        __builtin_amdgcn_s_setprio(1);
#pragma unroll
        for (int ks = 0; ks < 2; ++ks) {
            bf16x8 pa[2], vb[4];
#pragma unroll
            for (int mi = 0; mi < 2; ++mi)
                pa[mi] = *(const bf16x8*)(QP + (w * 32 + mi * 16 + lr) * PSTR + ks * 32 + lg * 8);
#pragma unroll
            for (int nd = 0; nd < 4; ++nd) {
                int d = nd * 16 + lr;
                vb[nd] = *(const bf16x8*)(Vt + d * PSTR + ((ks * 32 + lg * 8) ^ (((d >> 3) & 7) << 3)));
            }
#pragma unroll
            for (int nd = 0; nd < 4; ++nd)
#pragma unroll
                for (int mi = 0; mi < 2; ++mi)
                    o[nd][mi] = __builtin_amdgcn_mfma_f32_16x16x32_bf16(vb[nd], pa[mi], o[nd][mi], 0, 0, 0);
        }
        __builtin_amdgcn_s_setprio(0);
    }

    // ---- epilogue: lane holds O[d][q]; 4 consecutive d -> ushort4 store ----
#pragma unroll
    for (int mi = 0; mi < 2; ++mi) {
        float inv = 1.f / lrow[mi];
        int row = q0 + w * 32 + mi * 16 + lr;
        u16* op = outp + (size_t)(b * SEQ + row) * 1024 + h * 64 + lg * 4;
#pragma unroll
        for (int nd = 0; nd < 4; ++nd) {
            ushort4 u;
            u.x = f2bf(o[nd][mi][0] * inv); u.y = f2bf(o[nd][mi][1] * inv);
            u.z = f2bf(o[nd][mi][2] * inv); u.w = f2bf(o[nd][mi][3] * inv);
            *(ushort4*)(op + nd * 16) = u;
        }
    }
}

__global__ __launch_bounds__(256, 2) void attn_kernel(
    const u16* __restrict__ qkv, u16* __restrict__ outp)
{
    __shared__ __attribute__((aligned(16))) u16 QP[128 * PSTR];
    __shared__ __attribute__((aligned(16))) u16 Ks[64 * PSTR];
    __shared__ __attribute__((aligned(16))) u16 Vt[64 * PSTR];

    // XCD-aware remap: all 8 q-pair blocks of a (b,h) on one XCD ->
    // its K/V (512 KB) stays L2-resident.
    const int bid = (int)blockIdx.x + (int)blockIdx.y * 8;
    const int xcd = bid & 7;
    const int j   = bid >> 3;
    const int bh  = xcd * 8 + (j & 7);
    const int qp  = j >> 3;
    const int b   = bh >> 4, h = bh & 15;

    const u16* Qg = qkv + (size_t)b * SEQ * 3072 + h * 64;
    const u16* Kg = Qg + 1024;
    const u16* Vg = Qg + 2048;

    attn_qtile(Qg, Kg, Vg, outp, b, h, qp,           QP, Ks, Vt);
    attn_qtile(Qg, Kg, Vg, outp, b, h, NQT - 1 - qp, QP, Ks, Vt);
}

// ---------------------------------------------------------------------------
extern "C" void kernel_launch(void* const* d_in, const int* in_sizes, int n_in,
                              void* d_out, int out_size, void* d_ws, size_t ws_size,
                              hipStream_t stream)
{
    (void)in_sizes; (void)n_in; (void)out_size; (void)ws_size;
    const float* x  = (const float*)d_in[0];
    const float* Wq = (const float*)d_in[1];
    const float* Wk = (const float*)d_in[2];
    const float* Wv = (const float*)d_in[3];
    const float* Wo = (const float*)d_in[4];

    u16*   qkv = (u16*)d_ws;                     // [8192,3072] bf16
    u16*   xb  = qkv + (size_t)8192 * 3072;      // [8192,1024] bf16
    u16*   att = xb;                             // alias: xb dead after QKV GEMM
    u16*   w3  = (u16*)d_out;                    // Wq|Wk|Wv bf16 scratch
    u16*   wob = qkv;                            // Wo bf16 -> dead qkv region
    float* out = (float*)d_out;                  // final [8192,1024] fp32

    cvt_kernel <<<dim3(4096), 256, 0, stream>>>(x, xb, 1048576);
    cvt3_kernel<<<dim3(1536), 256, 0, stream>>>(Wq, Wk, Wv, w3);  // Wq pre-scaled 1/8

    gemm_qkv_kernel<<<dim3(64, 24), 256, 0, stream>>>(xb, w3, qkv);
    attn_kernel   <<<dim3(8, 64), 256, 0, stream>>>(qkv, att);

    cvt_kernel<<<dim3(512), 256, 0, stream>>>(Wo, wob, 131072);
    gemm_out_kernel<<<dim3(64, 8), 256, 0, stream>>>(att, wob, out);
}

// Round 5
// 272.277 us; speedup vs baseline: 1.6441x; 1.0126x over previous
//
#include <hip/hip_runtime.h>
#include <stdint.h>

typedef unsigned short u16;
typedef __attribute__((ext_vector_type(8))) __bf16 bf16x8;
typedef __attribute__((ext_vector_type(4))) float f32x4;

#define AS1 __attribute__((address_space(1)))
#define AS3 __attribute__((address_space(3)))
#define LOG2E 1.4426950408889634f

#define BAR() __builtin_amdgcn_s_barrier()
#define LGKM0() do { asm volatile("s_waitcnt lgkmcnt(0)" ::: "memory"); \
                     __builtin_amdgcn_sched_barrier(0); } while (0)
#define VMC6() asm volatile("s_waitcnt vmcnt(6)" ::: "memory")
#define VMC0() asm volatile("s_waitcnt vmcnt(0)" ::: "memory")

__device__ __forceinline__ u16 f2bf(float f) {
    union { __bf16 h; u16 u; } cv;
    cv.h = (__bf16)f;   // native cvt (RTNE)
    return cv.u;
}

__device__ __forceinline__ float vmax4(f32x4 x) {
    return fmaxf(fmaxf(x[0], x[1]), fmaxf(x[2], x[3]));
}
__device__ __forceinline__ float vsum4(f32x4 x) {
    return (x[0] + x[1]) + (x[2] + x[3]);
}

// ---------------------------------------------------------------------------
// fp32 -> bf16 convert, 8 elements/thread.
// ---------------------------------------------------------------------------
__global__ __launch_bounds__(256) void cvt_kernel(
    const float* __restrict__ src, u16* __restrict__ dst, int n8)
{
    int i = blockIdx.x * 256 + threadIdx.x;
    if (i >= n8) return;
    const float4* s = (const float4*)src;
    float4 f0 = s[(size_t)i * 2], f1 = s[(size_t)i * 2 + 1];
    ushort4 a, b;
    a.x = f2bf(f0.x); a.y = f2bf(f0.y); a.z = f2bf(f0.z); a.w = f2bf(f0.w);
    b.x = f2bf(f1.x); b.y = f2bf(f1.y); b.z = f2bf(f1.z); b.w = f2bf(f1.w);
    ((ushort4*)dst)[(size_t)i * 2]     = a;
    ((ushort4*)dst)[(size_t)i * 2 + 1] = b;
}

// Wq|Wk|Wv in one launch; Wq gets the 1/8 attention scale folded in.
__global__ __launch_bounds__(256) void cvt3_kernel(
    const float* __restrict__ wq, const float* __restrict__ wk,
    const float* __restrict__ wv, u16* __restrict__ dst)
{
    int i = blockIdx.x * 256 + threadIdx.x;
    int seg = i >> 17;
    const float* s = (seg == 0) ? wq : (seg == 1) ? wk : wv;
    float sc = (seg == 0) ? 0.125f : 1.0f;
    int j = i & 131071;
    const float4* sp = (const float4*)s;
    float4 f0 = sp[(size_t)j * 2], f1 = sp[(size_t)j * 2 + 1];
    ushort4 a, b;
    a.x = f2bf(f0.x * sc); a.y = f2bf(f0.y * sc); a.z = f2bf(f0.z * sc); a.w = f2bf(f0.w * sc);
    b.x = f2bf(f1.x * sc); b.y = f2bf(f1.y * sc); b.z = f2bf(f1.z * sc); b.w = f2bf(f1.w * sc);
    ((ushort4*)dst)[(size_t)i * 2]     = a;
    ((ushort4*)dst)[(size_t)i * 2 + 1] = b;
}

// ---------------------------------------------------------------------------
// 256x256 / BK=64 8-phase GEMM (QKV): C[8192,3072] = X[8192,1024] x W3^T.
// 512 threads (8 waves 2Mx4N); per-wave 128x64 out; LDS 128 KB 2-dbuf;
// G4 swizzle byte^=(row&7)<<4 both sides; counted vmcnt(6), never 0 in loop.
// ---------------------------------------------------------------------------
#define LDS_OFF(p, h) ((((p) * 4 + (h)) * 8192))

__device__ __forceinline__ void stage_A(
    const u16* __restrict__ G, int kt, int hm, u16* region, int t)
{
    int w6 = t & ~63;
#pragma unroll
    for (int i = 0; i < 2; ++i) {
        int s = i * 512 + t;
        int r = s >> 3;
        int j = (s & 7) ^ (r & 7);
        int row = (r & 63) + ((r >> 6) << 7) + (hm << 6);   // mh-interleaved
        const u16* g = G + (size_t)row * 1024 + kt * 64 + j * 8;
        u16* lp = region + (i * 512 + w6) * 8;              // wave-uniform base
        __builtin_amdgcn_global_load_lds((AS1 unsigned int*)g, (AS3 unsigned int*)lp, 16, 0, 0);
    }
}

__device__ __forceinline__ void stage_B(
    const u16* __restrict__ G, int kt, int hb, u16* region, int t)
{
    int w6 = t & ~63;
#pragma unroll
    for (int i = 0; i < 2; ++i) {
        int s = i * 512 + t;
        int r = s >> 3;
        int j = (s & 7) ^ (r & 7);
        int row = hb * 128 + r;
        const u16* g = G + (size_t)row * 1024 + kt * 64 + j * 8;
        u16* lp = region + (i * 512 + w6) * 8;
        __builtin_amdgcn_global_load_lds((AS1 unsigned int*)g, (AS3 unsigned int*)lp, 16, 0, 0);
    }
}

__device__ __forceinline__ bf16x8 fragr(const u16* region, int row, int j) {
    int byte = row * 128 + ((j ^ (row & 7)) << 4);
    return *(const bf16x8*)((const char*)region + byte);
}

__global__ __launch_bounds__(512, 2) void gemm_qkv_256(
    const u16* __restrict__ X, const u16* __restrict__ W3, u16* __restrict__ QKV)
{
    __shared__ __attribute__((aligned(16))) u16 lds[65536];   // 128 KB

    const int t  = threadIdx.x;
    const int l  = t & 63, w = t >> 6;
    const int wm = w >> 2, wn = w & 3;
    const int lr = l & 15, lg = l >> 4;

    // bijective XCD chunking: nwg=384=8*48; each XCD: 4 consecutive M-tiles x all N
    int bid = (int)blockIdx.x;
    int wg  = (bid & 7) * 48 + (bid >> 3);
    int mx  = wg / 12, ny = wg % 12;
    const int mb = mx * 256, nb = ny * 256;
    const u16* A = X  + (size_t)mb * 1024;
    const u16* B = W3 + (size_t)nb * 1024;

    const int NT = 16;   // K=1024 / BK=64

    // prologue: chronological order must be {A0,B0,B1,A1}[0], {A0,B0,B1}[1]
    stage_A(A, 0, 0, lds + LDS_OFF(0, 0), t);
    stage_B(B, 0, 0, lds + LDS_OFF(0, 2), t);
    stage_B(B, 0, 1, lds + LDS_OFF(0, 3), t);
    stage_A(A, 0, 1, lds + LDS_OFF(0, 1), t);
    stage_A(A, 1, 0, lds + LDS_OFF(1, 0), t);
    stage_B(B, 1, 0, lds + LDS_OFF(1, 2), t);
    stage_B(B, 1, 1, lds + LDS_OFF(1, 3), t);
    VMC6();
    BAR();

    f32x4 acc[8][4];
#pragma unroll
    for (int i = 0; i < 8; ++i)
#pragma unroll
        for (int j = 0; j < 4; ++j) acc[i][j] = f32x4{0.f, 0.f, 0.f, 0.f};

    for (int kt = 0; kt < NT; ++kt) {
        const int p = kt & 1;
        u16* A0r = lds + LDS_OFF(p, 0);
        u16* A1r = lds + LDS_OFF(p, 1);
        u16* B0r = lds + LDS_OFF(p, 2);
        u16* B1r = lds + LDS_OFF(p, 3);
        u16* A1n = lds + LDS_OFF(p ^ 1, 1);
        const u16* Bw = (wn >= 2) ? B1r : B0r;
        const int brow0 = (wn & 1) * 64;

        bf16x8 af[4][2], bf[4][2];

        // ---- ph1: read af(mh0)+bf01 (12 rd); stage A1[kt+1] (other buf) ----
#pragma unroll
        for (int mi = 0; mi < 4; ++mi)
#pragma unroll
            for (int ks = 0; ks < 2; ++ks)
                af[mi][ks] = fragr(A0r, wm * 64 + mi * 16 + lr, ks * 4 + lg);
#pragma unroll
        for (int ni = 0; ni < 2; ++ni)
#pragma unroll
            for (int ks = 0; ks < 2; ++ks)
                bf[ni][ks] = fragr(Bw, brow0 + ni * 16 + lr, ks * 4 + lg);
        if (kt + 1 < NT) stage_A(A, kt + 1, 1, A1n, t);
        BAR();
        LGKM0();
        __builtin_amdgcn_s_setprio(1);
#pragma unroll
        for (int mi = 0; mi < 4; ++mi)
#pragma unroll
            for (int ni = 0; ni < 2; ++ni)
#pragma unroll
                for (int ks = 0; ks < 2; ++ks)
                    acc[mi][ni] = __builtin_amdgcn_mfma_f32_16x16x32_bf16(af[mi][ks], bf[ni][ks], acc[mi][ni], 0, 0, 0);
        __builtin_amdgcn_s_setprio(0);
        BAR();

        // ---- ph2: read bf23 (4 rd); stage A0[kt+2] (A0 dead after ph1) ----
#pragma unroll
        for (int ni = 2; ni < 4; ++ni)
#pragma unroll
            for (int ks = 0; ks < 2; ++ks)
                bf[ni][ks] = fragr(Bw, brow0 + ni * 16 + lr, ks * 4 + lg);
        if (kt + 2 < NT) stage_A(A, kt + 2, 0, A0r, t);
        BAR();
        LGKM0();
        __builtin_amdgcn_s_setprio(1);
#pragma unroll
        for (int mi = 0; mi < 4; ++mi)
#pragma unroll
            for (int ni = 2; ni < 4; ++ni)
#pragma unroll
                for (int ks = 0; ks < 2; ++ks)
                    acc[mi][ni] = __builtin_amdgcn_mfma_f32_16x16x32_bf16(af[mi][ks], bf[ni][ks], acc[mi][ni], 0, 0, 0);
        __builtin_amdgcn_s_setprio(0);
        BAR();

        // ---- ph3: read af(mh1) (8 rd); stage B0[kt+2] (B dead after ph2) ----
#pragma unroll
        for (int mi = 0; mi < 4; ++mi)
#pragma unroll
            for (int ks = 0; ks < 2; ++ks)
                af[mi][ks] = fragr(A1r, wm * 64 + mi * 16 + lr, ks * 4 + lg);
        if (kt + 2 < NT) stage_B(B, kt + 2, 0, B0r, t);
        BAR();
        LGKM0();
        __builtin_amdgcn_s_setprio(1);
#pragma unroll
        for (int mi = 0; mi < 4; ++mi)
#pragma unroll
            for (int ni = 0; ni < 2; ++ni)
#pragma unroll
                for (int ks = 0; ks < 2; ++ks)
                    acc[4 + mi][ni] = __builtin_amdgcn_mfma_f32_16x16x32_bf16(af[mi][ks], bf[ni][ks], acc[4 + mi][ni], 0, 0, 0);
        __builtin_amdgcn_s_setprio(0);
        BAR();

        // ---- ph4: stage B1[kt+2]; counted vmcnt (lands tile kt+1 exactly) ----
        if (kt + 2 < NT) {
            stage_B(B, kt + 2, 1, B1r, t);
            VMC6();
        } else if (kt + 1 < NT) {
            VMC0();
        }
        BAR();
        __builtin_amdgcn_s_setprio(1);
#pragma unroll
        for (int mi = 0; mi < 4; ++mi)
#pragma unroll
            for (int ni = 2; ni < 4; ++ni)
#pragma unroll
                for (int ks = 0; ks < 2; ++ks)
                    acc[4 + mi][ni] = __builtin_amdgcn_mfma_f32_16x16x32_bf16(af[mi][ks], bf[ni][ks], acc[4 + mi][ni], 0, 0, 0);
        __builtin_amdgcn_s_setprio(0);
        BAR();
    }

    // epilogue
#pragma unroll
    for (int mi = 0; mi < 8; ++mi)
#pragma unroll
        for (int ni = 0; ni < 4; ++ni) {
            int col = nb + wn * 64 + ni * 16 + lr;
#pragma unroll
            for (int v = 0; v < 4; ++v) {
                int row = mb + wm * 128 + mi * 16 + lg * 4 + v;
                QKV[(size_t)row * 3072 + col] = f2bf(acc[mi][ni][v]);
            }
        }
}

// ---------------------------------------------------------------------------
// m97-style 128x128 GEMM (kept for the output projection).
// ---------------------------------------------------------------------------
__device__ __forceinline__ void gemm_tile_body_f32(
    const u16* __restrict__ A, const u16* __restrict__ B, float* __restrict__ Cp,
    int K, int ldc, int mb, int nb, u16* As, u16* Bs)
{
    const int t  = threadIdx.x;
    const int l  = t & 63, w = t >> 6;
    const int wm = w >> 1, wn = w & 1;
    const int lr = l & 15, lg = l >> 4;

    f32x4 acc[4][4];
#pragma unroll
    for (int i = 0; i < 4; ++i)
#pragma unroll
        for (int j = 0; j < 4; ++j) acc[i][j] = f32x4{0.f, 0.f, 0.f, 0.f};

    for (int k0 = 0; k0 < K; k0 += 32) {
        __syncthreads();
#pragma unroll
        for (int i = 0; i < 2; ++i) {
            int chunk = i * 256 + t;
            int row   = chunk >> 2;
            int c8    = (chunk & 3) << 3;
            const u16* ga = A + (size_t)(mb + row) * K + k0 + c8;
            const u16* gb = B + (size_t)(nb + row) * K + k0 + c8;
            u16* la = As + (i * 256 + w * 64) * 8;
            u16* lb = Bs + (i * 256 + w * 64) * 8;
            __builtin_amdgcn_global_load_lds((AS1 unsigned int*)ga, (AS3 unsigned int*)la, 16, 0, 0);
            __builtin_amdgcn_global_load_lds((AS1 unsigned int*)gb, (AS3 unsigned int*)lb, 16, 0, 0);
        }
        __syncthreads();
        bf16x8 af[4], bfr[4];
#pragma unroll
        for (int mi = 0; mi < 4; ++mi)
            af[mi] = *(const bf16x8*)(As + (wm * 64 + mi * 16 + lr) * 32 + lg * 8);
#pragma unroll
        for (int ni = 0; ni < 4; ++ni)
            bfr[ni] = *(const bf16x8*)(Bs + (wn * 64 + ni * 16 + lr) * 32 + lg * 8);
#pragma unroll
        for (int mi = 0; mi < 4; ++mi)
#pragma unroll
            for (int ni = 0; ni < 4; ++ni)
                acc[mi][ni] = __builtin_amdgcn_mfma_f32_16x16x32_bf16(af[mi], bfr[ni], acc[mi][ni], 0, 0, 0);
    }
#pragma unroll
    for (int mi = 0; mi < 4; ++mi)
#pragma unroll
        for (int ni = 0; ni < 4; ++ni) {
            int col = nb + wn * 64 + ni * 16 + lr;
#pragma unroll
            for (int v = 0; v < 4; ++v) {
                int row = mb + wm * 64 + mi * 16 + lg * 4 + v;
                Cp[(size_t)row * ldc + col] = acc[mi][ni][v];
            }
        }
}

__global__ __launch_bounds__(256, 2) void gemm_out_kernel(
    const u16* __restrict__ A, const u16* __restrict__ B, float* __restrict__ C)
{
    __shared__ __attribute__((aligned(16))) u16 As[128 * 32];
    __shared__ __attribute__((aligned(16))) u16 Bs[128 * 32];
    int bid = (int)blockIdx.x + (int)gridDim.x * (int)blockIdx.y;  // nwg=512
    int wg  = (bid & 7) * 64 + (bid >> 3);
    int mx  = wg >> 3;
    int my  = wg & 7;
    gemm_tile_body_f32(A, B, C, 1024, 1024, mx * 128, my * 128, As, Bs);
}

// ---------------------------------------------------------------------------
// Causal flash attention (swapped-operand MFMA; unchanged from R3).
// ---------------------------------------------------------------------------
#define SEQ  2048
#define PSTR 72
#define NQT  16

__device__ __forceinline__ void attn_qtile(
    const u16* __restrict__ Qg, const u16* __restrict__ Kg, const u16* __restrict__ Vg,
    u16* __restrict__ outp, int b, int h, int qt,
    u16* QP, u16* Ks, u16* Vt)
{
    const int t  = threadIdx.x;
    const int l  = t & 63, w = t >> 6;
    const int lr = l & 15, lg = l >> 4;
    const int q0 = qt * 128;
    const int sr = t >> 3;
    const int sc = (t & 7) << 3;
    const int vswz = sc;

    __syncthreads();
#pragma unroll
    for (int i = 0; i < 4; ++i) {
        int r = sr + i * 32;
        *(uint4*)(QP + r * PSTR + sc) = *(const uint4*)(Qg + (size_t)(q0 + r) * 3072 + sc);
    }
    __syncthreads();
    bf16x8 qf[2][2];
#pragma unroll
    for (int mi = 0; mi < 2; ++mi)
#pragma unroll
        for (int ks = 0; ks < 2; ++ks)
            qf[mi][ks] = *(const bf16x8*)(QP + (w * 32 + mi * 16 + lr) * PSTR + ks * 32 + lg * 8);

    uint4 kpf[2], vpf[2];
#pragma unroll
    for (int i = 0; i < 2; ++i) {
        int r = sr + i * 32;
        kpf[i] = *(const uint4*)(Kg + (size_t)r * 3072 + sc);
        vpf[i] = *(const uint4*)(Vg + (size_t)r * 3072 + sc);
    }

    f32x4 o[4][2];
#pragma unroll
    for (int nd = 0; nd < 4; ++nd)
#pragma unroll
        for (int mi = 0; mi < 2; ++mi) o[nd][mi] = f32x4{0.f, 0.f, 0.f, 0.f};
    float mrow[2]  = { -__builtin_inff(), -__builtin_inff() };
    float mrowL[2] = { -__builtin_inff(), -__builtin_inff() };
    float lrow[2]  = { 0.f, 0.f };

    const int nkt = 2 * qt + 2;
    for (int kt = 0; kt < nkt; ++kt) {
        const int k0 = kt * 64;
        __syncthreads();
#pragma unroll
        for (int i = 0; i < 2; ++i) {
            int r = sr + i * 32;
            *(uint4*)(Ks + r * PSTR + sc) = kpf[i];
            int rs = r ^ vswz;
            union { uint4 q; u16 u[8]; } uv; uv.q = vpf[i];
#pragma unroll
            for (int j = 0; j < 8; ++j)
                Vt[(sc + j) * PSTR + rs] = uv.u[j];
        }
        if (kt + 1 < nkt) {
            const int k0n = k0 + 64;
#pragma unroll
            for (int i = 0; i < 2; ++i) {
                int r = sr + i * 32;
                kpf[i] = *(const uint4*)(Kg + (size_t)(k0n + r) * 3072 + sc);
                vpf[i] = *(const uint4*)(Vg + (size_t)(k0n + r) * 3072 + sc);
            }
        }
        __syncthreads();

        f32x4 s[4][2];
#pragma unroll
        for (int ni = 0; ni < 4; ++ni)
#pragma unroll
            for (int mi = 0; mi < 2; ++mi) s[ni][mi] = f32x4{0.f, 0.f, 0.f, 0.f};
        __builtin_amdgcn_s_setprio(1);
#pragma unroll
        for (int ks = 0; ks < 2; ++ks) {
            bf16x8 kb[4];
#pragma unroll
            for (int ni = 0; ni < 4; ++ni)
                kb[ni] = *(const bf16x8*)(Ks + (ni * 16 + lr) * PSTR + ks * 32 + lg * 8);
#pragma unroll
            for (int ni = 0; ni < 4; ++ni)
#pragma unroll
                for (int mi = 0; mi < 2; ++mi)
                    s[ni][mi] = __builtin_amdgcn_mfma_f32_16x16x32_bf16(kb[ni], qf[mi][ks], s[ni][mi], 0, 0, 0);
        }
        __builtin_amdgcn_s_setprio(0);

#pragma unroll
        for (int mi = 0; mi < 2; ++mi) {
            if ((k0 + 63) > (q0 + w * 32 + mi * 16)) {
                int qpos = q0 + w * 32 + mi * 16 + lr;
#pragma unroll
                for (int ni = 0; ni < 4; ++ni) {
                    int kb0 = k0 + ni * 16 + lg * 4;
#pragma unroll
                    for (int v = 0; v < 4; ++v)
                        if (kb0 + v > qpos) s[ni][mi][v] = -__builtin_inff();
                }
            }
        }

        float rmax[2];
        bool grew = false;
#pragma unroll
        for (int mi = 0; mi < 2; ++mi) {
            float r = fmaxf(fmaxf(vmax4(s[0][mi]), vmax4(s[1][mi])),
                            fmaxf(vmax4(s[2][mi]), vmax4(s[3][mi])));
            r = fmaxf(r, __shfl_xor(r, 16));
            r = fmaxf(r, __shfl_xor(r, 32));
            rmax[mi] = r;
            grew |= (r > mrow[mi]);
        }
        if (__ballot(grew)) {
#pragma unroll
            for (int mi = 0; mi < 2; ++mi) {
                float mn  = fmaxf(mrow[mi], rmax[mi]);
                float mnL = mn * LOG2E;
                float al  = __builtin_amdgcn_exp2f(mrowL[mi] - mnL);
                mrow[mi]  = mn;
                mrowL[mi] = mnL;
                lrow[mi] *= al;
#pragma unroll
                for (int nd = 0; nd < 4; ++nd)
#pragma unroll
                    for (int v = 0; v < 4; ++v) o[nd][mi][v] *= al;
            }
        }
#pragma unroll
        for (int mi = 0; mi < 2; ++mi) {
            float nmL = -mrowL[mi];
#pragma unroll
            for (int ni = 0; ni < 4; ++ni)
#pragma unroll
                for (int v = 0; v < 4; ++v)
                    s[ni][mi][v] = __builtin_amdgcn_exp2f(
                        __builtin_fmaf(s[ni][mi][v], LOG2E, nmL));
            float sum = (vsum4(s[0][mi]) + vsum4(s[1][mi]))
                      + (vsum4(s[2][mi]) + vsum4(s[3][mi]));
            sum += __shfl_xor(sum, 16);
            sum += __shfl_xor(sum, 32);
            lrow[mi] += sum;
            int prow = (w * 32 + mi * 16 + lr) * PSTR + lg * 4;
#pragma unroll
            for (int ni = 0; ni < 4; ++ni) {
                ushort4 u;
                u.x = f2bf(s[ni][mi][0]); u.y = f2bf(s[ni][mi][1]);
                u.z = f2bf(s[ni][mi][2]); u.w = f2bf(s[ni][mi][3]);
                *(ushort4*)(QP + prow + ni * 16) = u;
            }
        }

        __builtin_amdgcn_s_setprio(1);
#pragma unroll
        for (int ks = 0; ks < 2; ++ks) {
            bf16x8 pa[2], vb[4];
#pragma unroll
            for (int mi = 0; mi < 2; ++mi)
                pa[mi] = *(const bf16x8*)(QP + (w * 32 + mi * 16 + lr) * PSTR + ks * 32 + lg * 8);
#pragma unroll
            for (int nd = 0; nd < 4; ++nd) {
                int d = nd * 16 + lr;
                vb[nd] = *(const bf16x8*)(Vt + d * PSTR + ((ks * 32 + lg * 8) ^ (((d >> 3) & 7) << 3)));
            }
#pragma unroll
            for (int nd = 0; nd < 4; ++nd)
#pragma unroll
                for (int mi = 0; mi < 2; ++mi)
                    o[nd][mi] = __builtin_amdgcn_mfma_f32_16x16x32_bf16(vb[nd], pa[mi], o[nd][mi], 0, 0, 0);
        }
        __builtin_amdgcn_s_setprio(0);
    }

#pragma unroll
    for (int mi = 0; mi < 2; ++mi) {
        float inv = 1.f / lrow[mi];
        int row = q0 + w * 32 + mi * 16 + lr;
        u16* op = outp + (size_t)(b * SEQ + row) * 1024 + h * 64 + lg * 4;
#pragma unroll
        for (int nd = 0; nd < 4; ++nd) {
            ushort4 u;
            u.x = f2bf(o[nd][mi][0] * inv); u.y = f2bf(o[nd][mi][1] * inv);
            u.z = f2bf(o[nd][mi][2] * inv); u.w = f2bf(o[nd][mi][3] * inv);
            *(ushort4*)(op + nd * 16) = u;
        }
    }
}

__global__ __launch_bounds__(256, 2) void attn_kernel(
    const u16* __restrict__ qkv, u16* __restrict__ outp)
{
    __shared__ __attribute__((aligned(16))) u16 QP[128 * PSTR];
    __shared__ __attribute__((aligned(16))) u16 Ks[64 * PSTR];
    __shared__ __attribute__((aligned(16))) u16 Vt[64 * PSTR];

    const int bid = (int)blockIdx.x + (int)blockIdx.y * 8;
    const int xcd = bid & 7;
    const int j   = bid >> 3;
    const int bh  = xcd * 8 + (j & 7);
    const int qp  = j >> 3;
    const int b   = bh >> 4, h = bh & 15;

    const u16* Qg = qkv + (size_t)b * SEQ * 3072 + h * 64;
    const u16* Kg = Qg + 1024;
    const u16* Vg = Qg + 2048;

    attn_qtile(Qg, Kg, Vg, outp, b, h, qp,           QP, Ks, Vt);
    attn_qtile(Qg, Kg, Vg, outp, b, h, NQT - 1 - qp, QP, Ks, Vt);
}

// ---------------------------------------------------------------------------
extern "C" void kernel_launch(void* const* d_in, const int* in_sizes, int n_in,
                              void* d_out, int out_size, void* d_ws, size_t ws_size,
                              hipStream_t stream)
{
    (void)in_sizes; (void)n_in; (void)out_size; (void)ws_size;
    const float* x  = (const float*)d_in[0];
    const float* Wq = (const float*)d_in[1];
    const float* Wk = (const float*)d_in[2];
    const float* Wv = (const float*)d_in[3];
    const float* Wo = (const float*)d_in[4];

    u16*   qkv = (u16*)d_ws;                     // [8192,3072] bf16
    u16*   xb  = qkv + (size_t)8192 * 3072;      // [8192,1024] bf16
    u16*   att = xb;                             // alias: xb dead after QKV GEMM
    u16*   w3  = (u16*)d_out;                    // Wq|Wk|Wv bf16 scratch
    u16*   wob = qkv;                            // Wo bf16 -> dead qkv region
    float* out = (float*)d_out;                  // final [8192,1024] fp32

    cvt_kernel <<<dim3(4096), 256, 0, stream>>>(x, xb, 1048576);
    cvt3_kernel<<<dim3(1536), 256, 0, stream>>>(Wq, Wk, Wv, w3);  // Wq pre-scaled 1/8

    gemm_qkv_256<<<dim3(384), 512, 0, stream>>>(xb, w3, qkv);
    attn_kernel <<<dim3(8, 64), 256, 0, stream>>>(qkv, att);

    cvt_kernel<<<dim3(512), 256, 0, stream>>>(Wo, wob, 131072);
    gemm_out_kernel<<<dim3(64, 8), 256, 0, stream>>>(att, wob, out);
}